// Round 3
// baseline (1537.991 us; speedup 1.0000x reference)
//
#include <hip/hip_runtime.h>
#include <stdint.h>

// 3-layer binary net as XNOR-popcount on bit-packed vectors.
// ws: X1p 65536*32 u32 @0 (8MB) | cA 256*1024 s8 | cB 256*1024 u8 | M1p 1024*32 u32 | M2p 24*32 u32
#define WS_CA  8388608
#define WS_CB  8650752
#define WS_M1  8912896
#define WS_M2  9043968

// ---- mask upload-format sniffing (bool arrays may arrive as u8, i32, or f32) ----
__device__ inline int detect_mode(const unsigned char* p) {
  unsigned nonalign = 0;
  for (int i = 0; i < 64; i++)
    if (i & 3) nonalign |= p[i];
  if (nonalign == 0) return 1;                 // int32 0/1
  bool f32ok = true;
  for (int e = 0; e < 16; e++) {
    const unsigned char* q = p + 4 * e;
    bool one  = (q[0] == 0 && q[1] == 0 && q[2] == 0x80 && q[3] == 0x3F);
    bool zero = (q[0] == 0 && q[1] == 0 && q[2] == 0 && q[3] == 0);
    if (!(one || zero)) { f32ok = false; break; }
  }
  return f32ok ? 2 : 0;
}

__device__ inline int maskbit(const unsigned char* p, int idx, int mode) {
  if (mode == 1) return ((const int*)p)[idx] & 1;
  if (mode == 2) return ((const float*)p)[idx] != 0.0f;
  return p[idx] & 1;
}

__global__ __launch_bounds__(256) void prep_kernel(
    const unsigned char* __restrict__ mask0, const int* __restrict__ thr0,
    const unsigned char* __restrict__ mask1, const unsigned char* __restrict__ mask2,
    signed char* __restrict__ cA, unsigned char* __restrict__ cB,
    unsigned* __restrict__ M1p, unsigned* __restrict__ M2p) {
  int mode = detect_mode(mask1);
  int gid = blockIdx.x * 256 + threadIdx.x;
  if (gid < 524288) {              // cA / cB tables
    int which = gid >> 18;         // 0 = cA (h-bits), 1 = cB (w-bits)
    int idx = gid & 262143;
    int hw = idx >> 10;
    int o  = idx & 1023;
    int base = which ? 8 : 0;
    int cnt = 0;
#pragma unroll
    for (int i = 0; i < 8; i++) {
      int xb = (hw >> (7 - i)) & 1;                     // MSB-first bits
      int mb = maskbit(mask0, (base + i) * 1024 + o, mode);
      cnt += (xb == mb);
    }
    if (which) cB[idx] = (unsigned char)cnt;
    else       cA[idx] = (signed char)(cnt - thr0[o]);  // fold threshold in
    return;
  }
  int g2 = gid - 524288;
  if (g2 < 32768) {                // pack mask1: M1p[o][kw], LSB-first bits
    int kw = g2 >> 10, o = g2 & 1023;
    unsigned wv = 0;
#pragma unroll
    for (int b = 0; b < 32; b++)
      wv |= (unsigned)maskbit(mask1, (kw * 32 + b) * 1024 + o, mode) << b;
    M1p[o * 32 + kw] = wv;
    return;
  }
  int g3 = g2 - 32768;
  if (g3 < 768) {                  // pack mask2: M2p[o][kw]
    int kw = g3 / 24, o = g3 % 24;
    unsigned wv = 0;
    for (int b = 0; b < 32; b++)
      wv |= (unsigned)maskbit(mask2, (kw * 32 + b) * 24 + o, mode) << b;
    M2p[o * 32 + kw] = wv;
  }
}

// Layer-0 evaluate + bit-pack. Block = (h, w-quarter): 64 pixels, cA row + cB rows L1/L2-hot.
__global__ __launch_bounds__(256) void pack_x1(
    const signed char* __restrict__ cA, const unsigned char* __restrict__ cB,
    unsigned* __restrict__ X1p) {
  int t = threadIdx.x;
  int lane = t & 63;
  int q = t >> 6;                  // wave id in block
  int h = blockIdx.x >> 2;
  int w0 = (blockIdx.x & 3) << 6;
  const signed char* ca = cA + h * 1024;
  for (int wi = 0; wi < 64; wi++) {
    int w = w0 + wi;
    const unsigned char* cb = cB + w * 1024;
    int n = h * 256 + w;
#pragma unroll
    for (int j = 0; j < 4; j++) {
      int o = j * 256 + t;
      bool bit = ((int)ca[o] + (int)cb[o]) > 0;        // cA+cB > thr0
      unsigned long long bal = __ballot(bit);
      if (lane == 0) {
        uint2 v; v.x = (unsigned)bal; v.y = (unsigned)(bal >> 32);
        *reinterpret_cast<uint2*>(&X1p[n * 32 + j * 8 + q * 2]) = v;
      }
    }
  }
}

// Main: L1 popcount-GEMM (128px x 1024out per block) + fused L2 + epilogue.
// LDS tiles are uint4-typed with uint4-granular XOR swizzle kq ^= (row&7).
// Read side: (row&7) is per-thread constant (sub-row stride 16), so each k-step
// needs one base address + 8 immediate-offset ds_read_b128 per operand.
__global__ __launch_bounds__(256, 3) void main_kernel(
    const uint4* __restrict__ X1p4, const uint4* __restrict__ M1p4,
    const unsigned* __restrict__ M2p, const int* __restrict__ thr1,
    const int* __restrict__ thr2, const float* __restrict__ image,
    float* __restrict__ out) {
  __shared__ uint4 lx4[1024];      // 16 KB  X tile  [row][kq^(row&7)]
  __shared__ uint4 lm4[1024];      // 16 KB  M tile  (bitb overlays after oc loop)
  __shared__ unsigned lx2[4096];   // 16 KB  x2 bits [p][k^(p&31)]
  __shared__ unsigned lm2[768];    //  3 KB  mask2 words
  int t = threadIdx.x;
  int n0 = blockIdx.x << 7;

#pragma unroll
  for (int i = 0; i < 4; i++) {
    int idx = t + i * 256;
    int row = idx >> 3;
    int kq = idx & 7;
    lx4[(row << 3) | (kq ^ (row & 7))] = X1p4[(n0 << 3) + idx];
  }
  for (int r = t; r < 768; r += 256) lm2[r] = M2p[r];   // FIX: full 768 words

  int oc_t = t & 15;               // output-thread 0..15
  int pr_t = t >> 4;               // pixel-thread 0..15
  int pgrp = pr_t & 3;             // pixel group within wave
  int sx = pr_t & 7;               // X-tile swizzle key (const per thread)
  int so = oc_t & 7;               // M-tile swizzle key

  for (int oc = 0; oc < 8; oc++) {
    __syncthreads();               // protect lm4 from previous iteration
#pragma unroll
    for (int i = 0; i < 4; i++) {
      int idx = t + i * 256;
      int row = idx >> 3;
      int kq = idx & 7;
      lm4[(row << 3) | (kq ^ (row & 7))] = M1p4[(oc << 10) + idx];
    }
    __syncthreads();

    unsigned acc[8][8];
#pragma unroll
    for (int i = 0; i < 8; i++)
#pragma unroll
      for (int j = 0; j < 8; j++) acc[i][j] = 0;

#pragma unroll
    for (int kq = 0; kq < 8; kq++) {
      const uint4* xp = &lx4[(pr_t << 3) + (kq ^ sx)];
      const uint4* mp = &lm4[(oc_t << 3) + (kq ^ so)];
      uint4 xv[8], mv[8];
#pragma unroll
      for (int i = 0; i < 8; i++) xv[i] = xp[i << 7];   // +i*2048B immediate
#pragma unroll
      for (int j = 0; j < 8; j++) mv[j] = mp[j << 7];
#pragma unroll
      for (int i = 0; i < 8; i++)
#pragma unroll
        for (int j = 0; j < 8; j++) {
          acc[i][j] += __popc(xv[i].x ^ mv[j].x);
          acc[i][j] += __popc(xv[i].y ^ mv[j].y);
          acc[i][j] += __popc(xv[i].z ^ mv[j].z);
          acc[i][j] += __popc(xv[i].w ^ mv[j].w);
        }
    }

    // threshold + ballot-pack x2 bits into lx2 (word index swizzled by p&31)
    int limv[8];
#pragma unroll
    for (int j = 0; j < 8; j++)
      limv[j] = 1024 - thr1[(oc << 7) + (j << 4) + oc_t];
#pragma unroll
    for (int i = 0; i < 8; i++) {
      unsigned wacc[4] = {0, 0, 0, 0};
#pragma unroll
      for (int j = 0; j < 8; j++) {
        bool bit = ((int)acc[i][j]) < limv[j];          // 1024-acc > thr1
        unsigned long long bal = __ballot(bit);
        unsigned hw16 = (unsigned)(bal >> (pgrp << 4)) & 0xFFFFu;
        wacc[j >> 1] |= hw16 << ((j & 1) << 4);
      }
      if (oc_t == 0) {
        int p = pr_t + (i << 4);
        int psw = p & 31;
#pragma unroll
        for (int wd = 0; wd < 4; wd++)
          lx2[p * 32 + (((oc << 2) + wd) ^ psw)] = wacc[wd];
      }
    }
  }
  __syncthreads();

  // layer 2: 128 px x 24 outputs (lx2 reads conflict-free via psw swizzle)
  unsigned char* bitb = reinterpret_cast<unsigned char*>(lm4);  // overlay
  for (int r = 0; r < 12; r++) {
    int item = t + (r << 8);
    int p = item & 127;
    int o = item >> 7;
    int psw = p & 31;
    unsigned acc2 = 0;
#pragma unroll
    for (int k = 0; k < 32; k++)
      acc2 += __popc(lx2[p * 32 + (k ^ psw)] ^ lm2[o * 32 + k]);
    bitb[p * 24 + o] = (unsigned char)(((int)(1024u - acc2)) > thr2[o]);
  }
  __syncthreads();

  // epilogue: bits -> int (MSB-first), minus image; harness reads d_out as f32
  if (t < 128) {
    int n = n0 + t;
#pragma unroll
    for (int c = 0; c < 3; c++) {
      int val = 0;
#pragma unroll
      for (int bb = 0; bb < 8; bb++)
        val |= ((int)bitb[t * 24 + c * 8 + bb]) << (7 - bb);
      out[c * 65536 + n] = (float)val;
      float img = image[c * 65536 + n];
      out[196608 + c * 65536 + n] = (float)val - img;
    }
  }
}

extern "C" void kernel_launch(void* const* d_in, const int* in_sizes, int n_in,
                              void* d_out, int out_size, void* d_ws, size_t ws_size,
                              hipStream_t stream) {
  const float*         image = (const float*)d_in[0];
  const unsigned char* mask0 = (const unsigned char*)d_in[1];
  const int*           thr0  = (const int*)d_in[2];
  const unsigned char* mask1 = (const unsigned char*)d_in[3];
  const int*           thr1  = (const int*)d_in[4];
  const unsigned char* mask2 = (const unsigned char*)d_in[5];
  const int*           thr2  = (const int*)d_in[6];
  char* ws = (char*)d_ws;
  unsigned*      X1p = (unsigned*)(ws);
  signed char*   cA  = (signed char*)(ws + WS_CA);
  unsigned char* cB  = (unsigned char*)(ws + WS_CB);
  unsigned*      M1p = (unsigned*)(ws + WS_M1);
  unsigned*      M2p = (unsigned*)(ws + WS_M2);
  float* out = (float*)d_out;

  hipLaunchKernelGGL(prep_kernel, dim3(2179), dim3(256), 0, stream,
                     mask0, thr0, mask1, mask2, cA, cB, M1p, M2p);
  hipLaunchKernelGGL(pack_x1, dim3(1024), dim3(256), 0, stream, cA, cB, X1p);
  hipLaunchKernelGGL(main_kernel, dim3(512), dim3(256), 0, stream,
                     (const uint4*)X1p, (const uint4*)M1p, M2p, thr1, thr2, image, out);
}

// Round 4
// 1147.960 us; speedup vs baseline: 1.3398x; 1.3398x over previous
//
#include <hip/hip_runtime.h>
#include <stdint.h>

// 3-layer binary net as XNOR-popcount on bit-packed vectors.
// ws: X1p 65536*32 u32 @0 (8MB) | cA 256*1024 s8 | cB 256*1024 u8 | M1p 1024*32 u32 | M2p 24*32 u32
#define WS_CA  8388608
#define WS_CB  8650752
#define WS_M1  8912896
#define WS_M2  9043968

// ---- mask upload-format sniffing (bool arrays may arrive as u8, i32, or f32) ----
__device__ inline int detect_mode(const unsigned char* p) {
  unsigned nonalign = 0;
  for (int i = 0; i < 64; i++)
    if (i & 3) nonalign |= p[i];
  if (nonalign == 0) return 1;                 // int32 0/1
  bool f32ok = true;
  for (int e = 0; e < 16; e++) {
    const unsigned char* q = p + 4 * e;
    bool one  = (q[0] == 0 && q[1] == 0 && q[2] == 0x80 && q[3] == 0x3F);
    bool zero = (q[0] == 0 && q[1] == 0 && q[2] == 0 && q[3] == 0);
    if (!(one || zero)) { f32ok = false; break; }
  }
  return f32ok ? 2 : 0;
}

__device__ inline int maskbit(const unsigned char* p, int idx, int mode) {
  if (mode == 1) return ((const int*)p)[idx] & 1;
  if (mode == 2) return ((const float*)p)[idx] != 0.0f;
  return p[idx] & 1;
}

__global__ __launch_bounds__(256) void prep_kernel(
    const unsigned char* __restrict__ mask0, const int* __restrict__ thr0,
    const unsigned char* __restrict__ mask1, const unsigned char* __restrict__ mask2,
    signed char* __restrict__ cA, unsigned char* __restrict__ cB,
    unsigned* __restrict__ M1p, unsigned* __restrict__ M2p) {
  int mode = detect_mode(mask1);
  int gid = blockIdx.x * 256 + threadIdx.x;
  if (gid < 524288) {              // cA / cB tables
    int which = gid >> 18;         // 0 = cA (h-bits), 1 = cB (w-bits)
    int idx = gid & 262143;
    int hw = idx >> 10;
    int o  = idx & 1023;
    int base = which ? 8 : 0;
    int cnt = 0;
#pragma unroll
    for (int i = 0; i < 8; i++) {
      int xb = (hw >> (7 - i)) & 1;                     // MSB-first bits
      int mb = maskbit(mask0, (base + i) * 1024 + o, mode);
      cnt += (xb == mb);
    }
    if (which) cB[idx] = (unsigned char)cnt;
    else       cA[idx] = (signed char)(cnt - thr0[o]);  // fold threshold in
    return;
  }
  int g2 = gid - 524288;
  if (g2 < 32768) {                // pack mask1: M1p[o][kw], LSB-first bits
    int kw = g2 >> 10, o = g2 & 1023;
    unsigned wv = 0;
#pragma unroll
    for (int b = 0; b < 32; b++)
      wv |= (unsigned)maskbit(mask1, (kw * 32 + b) * 1024 + o, mode) << b;
    M1p[o * 32 + kw] = wv;
    return;
  }
  int g3 = g2 - 32768;
  if (g3 < 768) {                  // pack mask2: M2p[o][kw]
    int kw = g3 / 24, o = g3 % 24;
    unsigned wv = 0;
    for (int b = 0; b < 32; b++)
      wv |= (unsigned)maskbit(mask2, (kw * 32 + b) * 24 + o, mode) << b;
    M2p[o * 32 + kw] = wv;
  }
}

// Layer-0 evaluate + bit-pack. Block = (h, w-quarter): 64 pixels, cA row + cB rows hot.
__global__ __launch_bounds__(256) void pack_x1(
    const signed char* __restrict__ cA, const unsigned char* __restrict__ cB,
    unsigned* __restrict__ X1p) {
  int t = threadIdx.x;
  int lane = t & 63;
  int q = t >> 6;                  // wave id in block
  int h = blockIdx.x >> 2;
  int w0 = (blockIdx.x & 3) << 6;
  const signed char* ca = cA + h * 1024;
  for (int wi = 0; wi < 64; wi++) {
    int w = w0 + wi;
    const unsigned char* cb = cB + w * 1024;
    int n = h * 256 + w;
#pragma unroll
    for (int j = 0; j < 4; j++) {
      int o = j * 256 + t;
      bool bit = ((int)ca[o] + (int)cb[o]) > 0;        // cA+cB > thr0
      unsigned long long bal = __ballot(bit);
      if (lane == 0) {
        uint2 v; v.x = (unsigned)bal; v.y = (unsigned)(bal >> 32);
        *reinterpret_cast<uint2*>(&X1p[n * 32 + j * 8 + q * 2]) = v;
      }
    }
  }
}

// Main: L1 popcount-GEMM (128px x 1024out per block) + fused L2 + epilogue.
// uint4-granular XOR swizzle kq ^= (row&7); read side (row&7) is per-thread
// constant so each operand = one base + immediate-offset ds_read_b128.
// launch_bounds(256,2): VGPR cap ~128 (compiler budgets ~256/min_waves — the
// (256,3)->84-VGPR spill disaster of R3 calibrated this). Live set kept ~110:
// acc[8][8]=64 + xv[4]=16 + streamed mv=4 + addressing.
__global__ __launch_bounds__(256, 2) void main_kernel(
    const uint4* __restrict__ X1p4, const uint4* __restrict__ M1p4,
    const unsigned* __restrict__ M2p, const int* __restrict__ thr1,
    const int* __restrict__ thr2, const float* __restrict__ image,
    float* __restrict__ out) {
  __shared__ uint4 lx4[1024];      // 16 KB  X tile  [row][kq^(row&7)]
  __shared__ uint4 lm4[1024];      // 16 KB  M tile  (bitb overlays after oc loop)
  __shared__ unsigned lx2[4096];   // 16 KB  x2 bits [p][k^(p&31)]
  __shared__ unsigned lm2[768];    //  3 KB  mask2 words
  int t = threadIdx.x;
  int n0 = blockIdx.x << 7;

#pragma unroll
  for (int i = 0; i < 4; i++) {
    int idx = t + i * 256;
    int row = idx >> 3;
    int kq = idx & 7;
    lx4[(row << 3) | (kq ^ (row & 7))] = X1p4[(n0 << 3) + idx];
  }
  for (int r = t; r < 768; r += 256) lm2[r] = M2p[r];

  int oc_t = t & 15;               // output-thread 0..15
  int pr_t = t >> 4;               // pixel-thread 0..15
  int pgrp = pr_t & 3;             // pixel group within wave
  int sx = pr_t & 7;               // X-tile swizzle key (const per thread)
  int so = oc_t & 7;               // M-tile swizzle key

  for (int oc = 0; oc < 8; oc++) {
    __syncthreads();               // protect lm4 from previous iteration
#pragma unroll
    for (int i = 0; i < 4; i++) {
      int idx = t + i * 256;
      int row = idx >> 3;
      int kq = idx & 7;
      lm4[(row << 3) | (kq ^ (row & 7))] = M1p4[(oc << 10) + idx];
    }
    __syncthreads();

    unsigned acc[8][8];
#pragma unroll
    for (int i = 0; i < 8; i++)
#pragma unroll
      for (int j = 0; j < 8; j++) acc[i][j] = 0;

#pragma unroll
    for (int kq = 0; kq < 8; kq++) {
      const uint4* xp = &lx4[(pr_t << 3) + (kq ^ sx)];
      const uint4* mp = &lm4[(oc_t << 3) + (kq ^ so)];
#pragma unroll
      for (int ih = 0; ih < 2; ih++) {
        uint4 xv[4];
#pragma unroll
        for (int ii = 0; ii < 4; ii++)
          xv[ii] = xp[(ih * 4 + ii) << 7];             // +2048B immediates
#pragma unroll
        for (int j = 0; j < 8; j++) {
          uint4 mv = mp[j << 7];                       // streamed, 4 regs live
#pragma unroll
          for (int ii = 0; ii < 4; ii++) {
            int i = ih * 4 + ii;
            acc[i][j] += __popc(xv[ii].x ^ mv.x);
            acc[i][j] += __popc(xv[ii].y ^ mv.y);
            acc[i][j] += __popc(xv[ii].z ^ mv.z);
            acc[i][j] += __popc(xv[ii].w ^ mv.w);
          }
        }
      }
    }

    // threshold + ballot-pack x2 bits into lx2 (word index swizzled by p&31)
    int limv[8];
#pragma unroll
    for (int j = 0; j < 8; j++)
      limv[j] = 1024 - thr1[(oc << 7) + (j << 4) + oc_t];
#pragma unroll
    for (int i = 0; i < 8; i++) {
      unsigned wacc[4] = {0, 0, 0, 0};
#pragma unroll
      for (int j = 0; j < 8; j++) {
        bool bit = ((int)acc[i][j]) < limv[j];          // 1024-acc > thr1
        unsigned long long bal = __ballot(bit);
        unsigned hw16 = (unsigned)(bal >> (pgrp << 4)) & 0xFFFFu;
        wacc[j >> 1] |= hw16 << ((j & 1) << 4);
      }
      if (oc_t == 0) {
        int p = pr_t + (i << 4);
        int psw = p & 31;
#pragma unroll
        for (int wd = 0; wd < 4; wd++)
          lx2[p * 32 + (((oc << 2) + wd) ^ psw)] = wacc[wd];
      }
    }
  }
  __syncthreads();

  // layer 2: 128 px x 24 outputs (lx2 reads conflict-free via psw swizzle)
  unsigned char* bitb = reinterpret_cast<unsigned char*>(lm4);  // overlay
  for (int r = 0; r < 12; r++) {
    int item = t + (r << 8);
    int p = item & 127;
    int o = item >> 7;
    int psw = p & 31;
    unsigned acc2 = 0;
#pragma unroll
    for (int k = 0; k < 32; k++)
      acc2 += __popc(lx2[p * 32 + (k ^ psw)] ^ lm2[o * 32 + k]);
    bitb[p * 24 + o] = (unsigned char)(((int)(1024u - acc2)) > thr2[o]);
  }
  __syncthreads();

  // epilogue: bits -> int (MSB-first), minus image; harness reads d_out as f32
  if (t < 128) {
    int n = n0 + t;
#pragma unroll
    for (int c = 0; c < 3; c++) {
      int val = 0;
#pragma unroll
      for (int bb = 0; bb < 8; bb++)
        val |= ((int)bitb[t * 24 + c * 8 + bb]) << (7 - bb);
      out[c * 65536 + n] = (float)val;
      float img = image[c * 65536 + n];
      out[196608 + c * 65536 + n] = (float)val - img;
    }
  }
}

extern "C" void kernel_launch(void* const* d_in, const int* in_sizes, int n_in,
                              void* d_out, int out_size, void* d_ws, size_t ws_size,
                              hipStream_t stream) {
  const float*         image = (const float*)d_in[0];
  const unsigned char* mask0 = (const unsigned char*)d_in[1];
  const int*           thr0  = (const int*)d_in[2];
  const unsigned char* mask1 = (const unsigned char*)d_in[3];
  const int*           thr1  = (const int*)d_in[4];
  const unsigned char* mask2 = (const unsigned char*)d_in[5];
  const int*           thr2  = (const int*)d_in[6];
  char* ws = (char*)d_ws;
  unsigned*      X1p = (unsigned*)(ws);
  signed char*   cA  = (signed char*)(ws + WS_CA);
  unsigned char* cB  = (unsigned char*)(ws + WS_CB);
  unsigned*      M1p = (unsigned*)(ws + WS_M1);
  unsigned*      M2p = (unsigned*)(ws + WS_M2);
  float* out = (float*)d_out;

  hipLaunchKernelGGL(prep_kernel, dim3(2179), dim3(256), 0, stream,
                     mask0, thr0, mask1, mask2, cA, cB, M1p, M2p);
  hipLaunchKernelGGL(pack_x1, dim3(1024), dim3(256), 0, stream, cA, cB, X1p);
  hipLaunchKernelGGL(main_kernel, dim3(512), dim3(256), 0, stream,
                     (const uint4*)X1p, (const uint4*)M1p, M2p, thr1, thr2, image, out);
}

// Round 5
// 627.355 us; speedup vs baseline: 2.4515x; 1.8298x over previous
//
#include <hip/hip_runtime.h>
#include <stdint.h>

// 3-layer binary net as XNOR-popcount on bit-packed vectors.
// ws: X1p 65536*32 u32 @0 (8MB) | cA 256*1024 s8 | cB 256*1024 u8 | M1p 1024*32 u32 | M2p 24*32 u32
#define WS_CA  8388608
#define WS_CB  8650752
#define WS_M1  8912896
#define WS_M2  9043968

// ---- mask upload-format sniffing (bool arrays may arrive as u8, i32, or f32) ----
__device__ inline int detect_mode(const unsigned char* p) {
  unsigned nonalign = 0;
  for (int i = 0; i < 64; i++)
    if (i & 3) nonalign |= p[i];
  if (nonalign == 0) return 1;                 // int32 0/1
  bool f32ok = true;
  for (int e = 0; e < 16; e++) {
    const unsigned char* q = p + 4 * e;
    bool one  = (q[0] == 0 && q[1] == 0 && q[2] == 0x80 && q[3] == 0x3F);
    bool zero = (q[0] == 0 && q[1] == 0 && q[2] == 0 && q[3] == 0);
    if (!(one || zero)) { f32ok = false; break; }
  }
  return f32ok ? 2 : 0;
}

__device__ inline int maskbit(const unsigned char* p, int idx, int mode) {
  if (mode == 1) return ((const int*)p)[idx] & 1;
  if (mode == 2) return ((const float*)p)[idx] != 0.0f;
  return p[idx] & 1;
}

__global__ __launch_bounds__(256) void prep_kernel(
    const unsigned char* __restrict__ mask0, const int* __restrict__ thr0,
    const unsigned char* __restrict__ mask1, const unsigned char* __restrict__ mask2,
    signed char* __restrict__ cA, unsigned char* __restrict__ cB,
    unsigned* __restrict__ M1p, unsigned* __restrict__ M2p) {
  int mode = detect_mode(mask1);
  int gid = blockIdx.x * 256 + threadIdx.x;
  if (gid < 524288) {              // cA / cB tables
    int which = gid >> 18;         // 0 = cA (h-bits), 1 = cB (w-bits)
    int idx = gid & 262143;
    int hw = idx >> 10;
    int o  = idx & 1023;
    int base = which ? 8 : 0;
    int cnt = 0;
#pragma unroll
    for (int i = 0; i < 8; i++) {
      int xb = (hw >> (7 - i)) & 1;                     // MSB-first bits
      int mb = maskbit(mask0, (base + i) * 1024 + o, mode);
      cnt += (xb == mb);
    }
    if (which) cB[idx] = (unsigned char)cnt;
    else       cA[idx] = (signed char)(cnt - thr0[o]);  // fold threshold in
    return;
  }
  int g2 = gid - 524288;
  if (g2 < 32768) {                // pack mask1: M1p[o][kw], LSB-first bits
    int kw = g2 >> 10, o = g2 & 1023;
    unsigned wv = 0;
#pragma unroll
    for (int b = 0; b < 32; b++)
      wv |= (unsigned)maskbit(mask1, (kw * 32 + b) * 1024 + o, mode) << b;
    M1p[o * 32 + kw] = wv;
    return;
  }
  int g3 = g2 - 32768;
  if (g3 < 768) {                  // pack mask2: M2p[o][kw]
    int kw = g3 / 24, o = g3 % 24;
    unsigned wv = 0;
    for (int b = 0; b < 32; b++)
      wv |= (unsigned)maskbit(mask2, (kw * 32 + b) * 24 + o, mode) << b;
    M2p[o * 32 + kw] = wv;
  }
}

// Layer-0 evaluate + bit-pack. Block = (h, w-quarter): 64 pixels, cA row + cB rows hot.
__global__ __launch_bounds__(256) void pack_x1(
    const signed char* __restrict__ cA, const unsigned char* __restrict__ cB,
    unsigned* __restrict__ X1p) {
  int t = threadIdx.x;
  int lane = t & 63;
  int q = t >> 6;                  // wave id in block
  int h = blockIdx.x >> 2;
  int w0 = (blockIdx.x & 3) << 6;
  const signed char* ca = cA + h * 1024;
  for (int wi = 0; wi < 64; wi++) {
    int w = w0 + wi;
    const unsigned char* cb = cB + w * 1024;
    int n = h * 256 + w;
#pragma unroll
    for (int j = 0; j < 4; j++) {
      int o = j * 256 + t;
      bool bit = ((int)ca[o] + (int)cb[o]) > 0;        // cA+cB > thr0
      unsigned long long bal = __ballot(bit);
      if (lane == 0) {
        uint2 v; v.x = (unsigned)bal; v.y = (unsigned)(bal >> 32);
        *reinterpret_cast<uint2*>(&X1p[n * 32 + j * 8 + q * 2]) = v;
      }
    }
  }
}

// Main: L1 popcount-GEMM. Block = 128px x 1024out; per oc-iteration 128px x 64out,
// per-thread acc[8][4] (32 regs) so the live set (~75) fits the (256,2) 128-VGPR
// budget with margin. R3/R4 lesson: never cap VGPR below the live set — shrink
// the live set. uint4-granular XOR swizzle kq^=(row&7); (row&7) is per-thread
// constant on the read side -> one base + immediate-offset ds_read_b128 chains.
__global__ __launch_bounds__(256, 2) void main_kernel(
    const uint4* __restrict__ X1p4, const uint4* __restrict__ M1p4,
    const unsigned* __restrict__ M2p, const int* __restrict__ thr1,
    const int* __restrict__ thr2, const float* __restrict__ image,
    float* __restrict__ out) {
  __shared__ uint4 lx4[1024];      // 16 KB  X tile  [row][kq^(row&7)]
  __shared__ uint4 lm4[512];       //  8 KB  M tile, 64 rows (bitb overlays later)
  __shared__ unsigned lx2[4096];   // 16 KB  x2 bits [p][k^(p&31)]
  __shared__ unsigned lm2[768];    //  3 KB  mask2 words
  int t = threadIdx.x;
  int n0 = blockIdx.x << 7;

#pragma unroll
  for (int i = 0; i < 4; i++) {
    int idx = t + i * 256;
    int row = idx >> 3;
    int kq = idx & 7;
    lx4[(row << 3) | (kq ^ (row & 7))] = X1p4[(n0 << 3) + idx];
  }
  for (int r = t; r < 768; r += 256) lm2[r] = M2p[r];

  int oc_t = t & 15;               // output-thread 0..15 (owns 4 outs, stride 16)
  int pr_t = t >> 4;               // pixel-thread 0..15 (owns 8 px, stride 16)
  int pgrp = pr_t & 3;             // pixel group within wave
  int sx = pr_t & 7;               // X-tile swizzle key (const per thread)
  int so = oc_t & 7;               // M-tile swizzle key

  for (int oc = 0; oc < 16; oc++) {
    __syncthreads();               // protect lm4 from previous iteration
#pragma unroll
    for (int i = 0; i < 2; i++) {
      int idx = t + i * 256;       // 512 uint4 = 64 rows x 8
      int row = idx >> 3;
      int kq = idx & 7;
      lm4[(row << 3) | (kq ^ (row & 7))] = M1p4[(oc << 9) + idx];
    }
    __syncthreads();

    unsigned acc[8][4];
#pragma unroll
    for (int i = 0; i < 8; i++)
#pragma unroll
      for (int j = 0; j < 4; j++) acc[i][j] = 0;

#pragma unroll
    for (int kq = 0; kq < 8; kq++) {
      const uint4* xp = &lx4[(pr_t << 3) + (kq ^ sx)];
      const uint4* mp = &lm4[(oc_t << 3) + (kq ^ so)];
#pragma unroll
      for (int ih = 0; ih < 2; ih++) {
        uint4 xv[4];
#pragma unroll
        for (int ii = 0; ii < 4; ii++)
          xv[ii] = xp[(ih * 4 + ii) << 7];             // +2048B immediates
#pragma unroll
        for (int j = 0; j < 4; j++) {
          uint4 mv = mp[j << 7];                       // streamed, 4 regs live
#pragma unroll
          for (int ii = 0; ii < 4; ii++) {
            int i = ih * 4 + ii;
            acc[i][j] += __popc(xv[ii].x ^ mv.x);
            acc[i][j] += __popc(xv[ii].y ^ mv.y);
            acc[i][j] += __popc(xv[ii].z ^ mv.z);
            acc[i][j] += __popc(xv[ii].w ^ mv.w);
          }
        }
      }
    }

    // threshold + ballot-pack x2 bits into lx2 (word index swizzled by p&31)
    int limv[4];
#pragma unroll
    for (int j = 0; j < 4; j++)
      limv[j] = 1024 - thr1[(oc << 6) + (j << 4) + oc_t];
#pragma unroll
    for (int i = 0; i < 8; i++) {
      unsigned wacc[2] = {0, 0};
#pragma unroll
      for (int j = 0; j < 4; j++) {
        bool bit = ((int)acc[i][j]) < limv[j];          // 1024-acc > thr1
        unsigned long long bal = __ballot(bit);
        unsigned hw16 = (unsigned)(bal >> (pgrp << 4)) & 0xFFFFu;
        wacc[j >> 1] |= hw16 << ((j & 1) << 4);
      }
      if (oc_t == 0) {
        int p = pr_t + (i << 4);
        int psw = p & 31;
#pragma unroll
        for (int wd = 0; wd < 2; wd++)
          lx2[p * 32 + (((oc << 1) + wd) ^ psw)] = wacc[wd];
      }
    }
  }
  __syncthreads();

  // layer 2: 128 px x 24 outputs (lx2 reads conflict-free via psw swizzle)
  unsigned char* bitb = reinterpret_cast<unsigned char*>(lm4);  // overlay (3KB<8KB)
  for (int r = 0; r < 12; r++) {
    int item = t + (r << 8);
    int p = item & 127;
    int o = item >> 7;
    int psw = p & 31;
    unsigned acc2 = 0;
#pragma unroll
    for (int k = 0; k < 32; k++)
      acc2 += __popc(lx2[p * 32 + (k ^ psw)] ^ lm2[o * 32 + k]);
    bitb[p * 24 + o] = (unsigned char)(((int)(1024u - acc2)) > thr2[o]);
  }
  __syncthreads();

  // epilogue: bits -> int (MSB-first), minus image; harness reads d_out as f32
  if (t < 128) {
    int n = n0 + t;
#pragma unroll
    for (int c = 0; c < 3; c++) {
      int val = 0;
#pragma unroll
      for (int bb = 0; bb < 8; bb++)
        val |= ((int)bitb[t * 24 + c * 8 + bb]) << (7 - bb);
      out[c * 65536 + n] = (float)val;
      float img = image[c * 65536 + n];
      out[196608 + c * 65536 + n] = (float)val - img;
    }
  }
}

extern "C" void kernel_launch(void* const* d_in, const int* in_sizes, int n_in,
                              void* d_out, int out_size, void* d_ws, size_t ws_size,
                              hipStream_t stream) {
  const float*         image = (const float*)d_in[0];
  const unsigned char* mask0 = (const unsigned char*)d_in[1];
  const int*           thr0  = (const int*)d_in[2];
  const unsigned char* mask1 = (const unsigned char*)d_in[3];
  const int*           thr1  = (const int*)d_in[4];
  const unsigned char* mask2 = (const unsigned char*)d_in[5];
  const int*           thr2  = (const int*)d_in[6];
  char* ws = (char*)d_ws;
  unsigned*      X1p = (unsigned*)(ws);
  signed char*   cA  = (signed char*)(ws + WS_CA);
  unsigned char* cB  = (unsigned char*)(ws + WS_CB);
  unsigned*      M1p = (unsigned*)(ws + WS_M1);
  unsigned*      M2p = (unsigned*)(ws + WS_M2);
  float* out = (float*)d_out;

  hipLaunchKernelGGL(prep_kernel, dim3(2179), dim3(256), 0, stream,
                     mask0, thr0, mask1, mask2, cA, cB, M1p, M2p);
  hipLaunchKernelGGL(pack_x1, dim3(1024), dim3(256), 0, stream, cA, cB, X1p);
  hipLaunchKernelGGL(main_kernel, dim3(512), dim3(256), 0, stream,
                     (const uint4*)X1p, (const uint4*)M1p, M2p, thr1, thr2, image, out);
}

// Round 6
// 225.701 us; speedup vs baseline: 6.8143x; 2.7796x over previous
//
#include <hip/hip_runtime.h>
#include <stdint.h>

// 3-layer binary net as XNOR-popcount on bit-packed vectors.
// ws: X1p 65536*32 u32 @0 (8MB) | cA 256*1024 s8 | cB 256*1024 u8 | M1p 1024*32 u32 | M2p 24*32 u32
#define WS_CA  8388608
#define WS_CB  8650752
#define WS_M1  8912896
#define WS_M2  9043968

// ---- mask upload-format sniffing (bool arrays may arrive as u8, i32, or f32) ----
__device__ inline int detect_mode(const unsigned char* p) {
  unsigned nonalign = 0;
  for (int i = 0; i < 64; i++)
    if (i & 3) nonalign |= p[i];
  if (nonalign == 0) return 1;                 // int32 0/1
  bool f32ok = true;
  for (int e = 0; e < 16; e++) {
    const unsigned char* q = p + 4 * e;
    bool one  = (q[0] == 0 && q[1] == 0 && q[2] == 0x80 && q[3] == 0x3F);
    bool zero = (q[0] == 0 && q[1] == 0 && q[2] == 0 && q[3] == 0);
    if (!(one || zero)) { f32ok = false; break; }
  }
  return f32ok ? 2 : 0;
}

__device__ inline int maskbit(const unsigned char* p, int idx, int mode) {
  if (mode == 1) return ((const int*)p)[idx] & 1;
  if (mode == 2) return ((const float*)p)[idx] != 0.0f;
  return p[idx] & 1;
}

__global__ __launch_bounds__(256) void prep_kernel(
    const unsigned char* __restrict__ mask0, const int* __restrict__ thr0,
    const unsigned char* __restrict__ mask1, const unsigned char* __restrict__ mask2,
    signed char* __restrict__ cA, unsigned char* __restrict__ cB,
    unsigned* __restrict__ M1p, unsigned* __restrict__ M2p) {
  int mode = detect_mode(mask1);
  int gid = blockIdx.x * 256 + threadIdx.x;
  if (gid < 524288) {              // cA / cB tables
    int which = gid >> 18;         // 0 = cA (h-bits), 1 = cB (w-bits)
    int idx = gid & 262143;
    int hw = idx >> 10;
    int o  = idx & 1023;
    int base = which ? 8 : 0;
    int cnt = 0;
#pragma unroll
    for (int i = 0; i < 8; i++) {
      int xb = (hw >> (7 - i)) & 1;                     // MSB-first bits
      int mb = maskbit(mask0, (base + i) * 1024 + o, mode);
      cnt += (xb == mb);
    }
    if (which) cB[idx] = (unsigned char)cnt;
    else       cA[idx] = (signed char)(cnt - thr0[o]);  // fold threshold in
    return;
  }
  int g2 = gid - 524288;
  if (g2 < 32768) {                // pack mask1: M1p[o][kw], LSB-first bits
    int kw = g2 >> 10, o = g2 & 1023;
    unsigned wv = 0;
#pragma unroll
    for (int b = 0; b < 32; b++)
      wv |= (unsigned)maskbit(mask1, (kw * 32 + b) * 1024 + o, mode) << b;
    M1p[o * 32 + kw] = wv;
    return;
  }
  int g3 = g2 - 32768;
  if (g3 < 768) {                  // pack mask2: M2p[o][kw]
    int kw = g3 / 24, o = g3 % 24;
    unsigned wv = 0;
    for (int b = 0; b < 32; b++)
      wv |= (unsigned)maskbit(mask2, (kw * 32 + b) * 24 + o, mode) << b;
    M2p[o * 32 + kw] = wv;
  }
}

// Layer-0 evaluate + bit-pack. Block = (h, w-quarter): 64 pixels, cA row + cB rows hot.
__global__ __launch_bounds__(256) void pack_x1(
    const signed char* __restrict__ cA, const unsigned char* __restrict__ cB,
    unsigned* __restrict__ X1p) {
  int t = threadIdx.x;
  int lane = t & 63;
  int q = t >> 6;                  // wave id in block
  int h = blockIdx.x >> 2;
  int w0 = (blockIdx.x & 3) << 6;
  const signed char* ca = cA + h * 1024;
  for (int wi = 0; wi < 64; wi++) {
    int w = w0 + wi;
    const unsigned char* cb = cB + w * 1024;
    int n = h * 256 + w;
#pragma unroll
    for (int j = 0; j < 4; j++) {
      int o = j * 256 + t;
      bool bit = ((int)ca[o] + (int)cb[o]) > 0;        // cA+cB > thr0
      unsigned long long bal = __ballot(bit);
      if (lane == 0) {
        uint2 v; v.x = (unsigned)bal; v.y = (unsigned)(bal >> 32);
        *reinterpret_cast<uint2*>(&X1p[n * 32 + j * 8 + q * 2]) = v;
      }
    }
  }
}

// Main: L1 popcount-GEMM. Block = 128px x 1024out, per oc-iteration 128x128,
// per-thread 8x8 acc (R2 geometry: 32:1 VALU:LDS-read ratio keeps LDS under
// the VALU floor). R3-R5 lesson: do NOT cap VGPRs below the live set, and do
// NOT fully unroll the k-loop (scheduler hoists all loads -> live-range blowup
// -> spill). kq is a real loop (#pragma unroll 1) bounding the live set to
// ~130 (acc 64 + xv 32 + streamed mv + addressing); no min-waves bound.
__global__ __launch_bounds__(256) void main_kernel(
    const uint4* __restrict__ X1p4, const uint4* __restrict__ M1p4,
    const unsigned* __restrict__ M2p, const int* __restrict__ thr1,
    const int* __restrict__ thr2, const float* __restrict__ image,
    float* __restrict__ out) {
  __shared__ uint4 lx4[1024];      // 16 KB  X tile  [row][kq^(row&7)]
  __shared__ uint4 lm4[1024];      // 16 KB  M tile  (bitb overlays later)
  __shared__ unsigned lx2[4096];   // 16 KB  x2 bits [p][k^(p&31)]
  __shared__ unsigned lm2[768];    //  3 KB  mask2 words
  int t = threadIdx.x;
  int n0 = blockIdx.x << 7;

#pragma unroll
  for (int i = 0; i < 4; i++) {
    int idx = t + i * 256;
    int row = idx >> 3;
    int kq = idx & 7;
    lx4[(row << 3) | (kq ^ (row & 7))] = X1p4[(n0 << 3) + idx];
  }
  for (int r = t; r < 768; r += 256) lm2[r] = M2p[r];

  int oc_t = t & 15;               // output-thread 0..15 (owns 8 outs, stride 16)
  int pr_t = t >> 4;               // pixel-thread 0..15 (owns 8 px, stride 16)
  int pgrp = pr_t & 3;             // pixel group within wave
  int sx = pr_t & 7;               // X-tile swizzle key (const per thread)
  int so = oc_t & 7;               // M-tile swizzle key

  for (int oc = 0; oc < 8; oc++) {
    __syncthreads();               // protect lm4 from previous iteration
#pragma unroll
    for (int i = 0; i < 4; i++) {
      int idx = t + i * 256;
      int row = idx >> 3;
      int kq = idx & 7;
      lm4[(row << 3) | (kq ^ (row & 7))] = M1p4[(oc << 10) + idx];
    }
    __syncthreads();

    unsigned acc[8][8];
#pragma unroll
    for (int i = 0; i < 8; i++)
#pragma unroll
      for (int j = 0; j < 8; j++) acc[i][j] = 0;

#pragma unroll 1
    for (int kq = 0; kq < 8; kq++) {
      const uint4* xp = &lx4[(pr_t << 3) + (kq ^ sx)];
      const uint4* mp = &lm4[(oc_t << 3) + (kq ^ so)];
      uint4 xv[8];
#pragma unroll
      for (int i = 0; i < 8; i++) xv[i] = xp[i << 7];   // +2048B immediates
#pragma unroll
      for (int j = 0; j < 8; j++) {
        uint4 mv = mp[j << 7];                          // streamed, ~4 regs live
#pragma unroll
        for (int i = 0; i < 8; i++) {
          acc[i][j] += __popc(xv[i].x ^ mv.x);
          acc[i][j] += __popc(xv[i].y ^ mv.y);
          acc[i][j] += __popc(xv[i].z ^ mv.z);
          acc[i][j] += __popc(xv[i].w ^ mv.w);
        }
      }
    }

    // threshold + ballot-pack x2 bits into lx2 (word index swizzled by p&31)
    int limv[8];
#pragma unroll
    for (int j = 0; j < 8; j++)
      limv[j] = 1024 - thr1[(oc << 7) + (j << 4) + oc_t];
#pragma unroll
    for (int i = 0; i < 8; i++) {
      unsigned wacc[4] = {0, 0, 0, 0};
#pragma unroll
      for (int j = 0; j < 8; j++) {
        bool bit = ((int)acc[i][j]) < limv[j];          // 1024-acc > thr1
        unsigned long long bal = __ballot(bit);
        unsigned hw16 = (unsigned)(bal >> (pgrp << 4)) & 0xFFFFu;
        wacc[j >> 1] |= hw16 << ((j & 1) << 4);
      }
      if (oc_t == 0) {
        int p = pr_t + (i << 4);
        int psw = p & 31;
#pragma unroll
        for (int wd = 0; wd < 4; wd++)
          lx2[p * 32 + (((oc << 2) + wd) ^ psw)] = wacc[wd];
      }
    }
  }
  __syncthreads();

  // layer 2: 128 px x 24 outputs (lx2 reads conflict-free via psw swizzle)
  unsigned char* bitb = reinterpret_cast<unsigned char*>(lm4);  // overlay
  for (int r = 0; r < 12; r++) {
    int item = t + (r << 8);
    int p = item & 127;
    int o = item >> 7;
    int psw = p & 31;
    unsigned acc2 = 0;
#pragma unroll
    for (int k = 0; k < 32; k++)
      acc2 += __popc(lx2[p * 32 + (k ^ psw)] ^ lm2[o * 32 + k]);
    bitb[p * 24 + o] = (unsigned char)(((int)(1024u - acc2)) > thr2[o]);
  }
  __syncthreads();

  // epilogue: bits -> int (MSB-first), minus image; harness reads d_out as f32
  if (t < 128) {
    int n = n0 + t;
#pragma unroll
    for (int c = 0; c < 3; c++) {
      int val = 0;
#pragma unroll
      for (int bb = 0; bb < 8; bb++)
        val |= ((int)bitb[t * 24 + c * 8 + bb]) << (7 - bb);
      out[c * 65536 + n] = (float)val;
      float img = image[c * 65536 + n];
      out[196608 + c * 65536 + n] = (float)val - img;
    }
  }
}

extern "C" void kernel_launch(void* const* d_in, const int* in_sizes, int n_in,
                              void* d_out, int out_size, void* d_ws, size_t ws_size,
                              hipStream_t stream) {
  const float*         image = (const float*)d_in[0];
  const unsigned char* mask0 = (const unsigned char*)d_in[1];
  const int*           thr0  = (const int*)d_in[2];
  const unsigned char* mask1 = (const unsigned char*)d_in[3];
  const int*           thr1  = (const int*)d_in[4];
  const unsigned char* mask2 = (const unsigned char*)d_in[5];
  const int*           thr2  = (const int*)d_in[6];
  char* ws = (char*)d_ws;
  unsigned*      X1p = (unsigned*)(ws);
  signed char*   cA  = (signed char*)(ws + WS_CA);
  unsigned char* cB  = (unsigned char*)(ws + WS_CB);
  unsigned*      M1p = (unsigned*)(ws + WS_M1);
  unsigned*      M2p = (unsigned*)(ws + WS_M2);
  float* out = (float*)d_out;

  hipLaunchKernelGGL(prep_kernel, dim3(2179), dim3(256), 0, stream,
                     mask0, thr0, mask1, mask2, cA, cB, M1p, M2p);
  hipLaunchKernelGGL(pack_x1, dim3(1024), dim3(256), 0, stream, cA, cB, X1p);
  hipLaunchKernelGGL(main_kernel, dim3(512), dim3(256), 0, stream,
                     (const uint4*)X1p, (const uint4*)M1p, M2p, thr1, thr2, image, out);
}

// Round 7
// 217.894 us; speedup vs baseline: 7.0584x; 1.0358x over previous
//
#include <hip/hip_runtime.h>
#include <stdint.h>

// 3-layer binary net as XNOR-popcount on bit-packed vectors.
// ws: X1p 65536*32 u32 @0 (8MB) | cA 256*1024 s8 | cB 256*1024 u8 |
//     M1p 1024*32 u32 | M2p 24*32 u32 | X2p 65536*32 u32 (8MB)
#define WS_CA  8388608
#define WS_CB  8650752
#define WS_M1  8912896
#define WS_M2  9043968
#define WS_X2  9047040

// ---- mask upload-format sniffing (bool arrays may arrive as u8, i32, or f32) ----
__device__ inline int detect_mode(const unsigned char* p) {
  unsigned nonalign = 0;
  for (int i = 0; i < 64; i++)
    if (i & 3) nonalign |= p[i];
  if (nonalign == 0) return 1;                 // int32 0/1
  bool f32ok = true;
  for (int e = 0; e < 16; e++) {
    const unsigned char* q = p + 4 * e;
    bool one  = (q[0] == 0 && q[1] == 0 && q[2] == 0x80 && q[3] == 0x3F);
    bool zero = (q[0] == 0 && q[1] == 0 && q[2] == 0 && q[3] == 0);
    if (!(one || zero)) { f32ok = false; break; }
  }
  return f32ok ? 2 : 0;
}

__device__ inline int maskbit(const unsigned char* p, int idx, int mode) {
  if (mode == 1) return ((const int*)p)[idx] & 1;
  if (mode == 2) return ((const float*)p)[idx] != 0.0f;
  return p[idx] & 1;
}

__global__ __launch_bounds__(256) void prep_kernel(
    const unsigned char* __restrict__ mask0, const int* __restrict__ thr0,
    const unsigned char* __restrict__ mask1, const unsigned char* __restrict__ mask2,
    signed char* __restrict__ cA, unsigned char* __restrict__ cB,
    unsigned* __restrict__ M1p, unsigned* __restrict__ M2p) {
  int mode = detect_mode(mask1);
  int gid = blockIdx.x * 256 + threadIdx.x;
  if (gid < 524288) {              // cA / cB tables (mask0 16KB, L1-hot)
    int which = gid >> 18;         // 0 = cA (h-bits), 1 = cB (w-bits)
    int idx = gid & 262143;
    int hw = idx >> 10;
    int o  = idx & 1023;
    int base = which ? 8 : 0;
    int cnt = 0;
#pragma unroll
    for (int i = 0; i < 8; i++) {
      int xb = (hw >> (7 - i)) & 1;                     // MSB-first bits
      int mb = maskbit(mask0, (base + i) * 1024 + o, mode);
      cnt += (xb == mb);
    }
    if (which) cB[idx] = (unsigned char)cnt;
    else       cA[idx] = (signed char)(cnt - thr0[o]);  // fold threshold in
    return;
  }
  int g2 = gid - 524288;
  if (g2 < 32768) {                // pack mask1: M1p[o][kw]; lanes->consecutive o = coalesced
    int kw = g2 >> 10, o = g2 & 1023;
    unsigned wv = 0;
#pragma unroll
    for (int b = 0; b < 32; b++)
      wv |= (unsigned)maskbit(mask1, (kw * 32 + b) * 1024 + o, mode) << b;  // LSB-first
    M1p[o * 32 + kw] = wv;
    return;
  }
  int g3 = g2 - 32768;
  if (g3 < 768) {                  // pack mask2: M2p[o][kw]
    int kw = g3 / 24, o = g3 % 24;
    unsigned wv = 0;
    for (int b = 0; b < 32; b++)
      wv |= (unsigned)maskbit(mask2, (kw * 32 + b) * 24 + o, mode) << b;
    M2p[o * 32 + kw] = wv;
  }
}

// Layer-0 evaluate + bit-pack. Block = (h, w/16): 16 pixels -> 4096 blocks
// (16/CU) so block-level parallelism hides the per-wi cb-row load latency.
__global__ __launch_bounds__(256) void pack_x1(
    const signed char* __restrict__ cA, const unsigned char* __restrict__ cB,
    unsigned* __restrict__ X1p) {
  int t = threadIdx.x;
  int lane = t & 63;
  int q = t >> 6;                  // wave id in block
  int h = blockIdx.x >> 4;
  int w0 = (blockIdx.x & 15) << 4;
  const signed char* ca = cA + h * 1024;
  for (int wi = 0; wi < 16; wi++) {
    int w = w0 + wi;
    const unsigned char* cb = cB + w * 1024;
    int n = h * 256 + w;
#pragma unroll
    for (int j = 0; j < 4; j++) {
      int o = j * 256 + t;
      bool bit = ((int)ca[o] + (int)cb[o]) > 0;        // cA+cB > thr0
      unsigned long long bal = __ballot(bit);
      if (lane == 0) {
        uint2 v; v.x = (unsigned)bal; v.y = (unsigned)(bal >> 32);
        *reinterpret_cast<uint2*>(&X1p[n * 32 + j * 8 + q * 2]) = v;
      }
    }
  }
}

// Main: L1 popcount-GEMM. Block = 128px x 512out (half the outputs; grid
// 1024 = 4 blocks/CU, VGPR 116 -> 4 waves/SIMD exactly). Per oc-iteration
// 128x128, per-thread 8x8 acc. R3-R6 lessons: no VGPR cap below live set; kq
// as a real loop (#pragma unroll 1) so scheduler can't balloon live ranges.
// uint4-granular XOR swizzle kq^=(row&7); (row&7) per-thread constant on the
// read side -> one base + immediate-offset ds_read_b128 chains.
// x2 bits go to global X2p (L2/epilogue run in a separate tiny kernel).
__global__ __launch_bounds__(256) void main_kernel(
    const uint4* __restrict__ X1p4, const uint4* __restrict__ M1p4,
    const int* __restrict__ thr1, unsigned* __restrict__ X2p) {
  __shared__ uint4 lx4[1024];      // 16 KB  X tile  [row][kq^(row&7)]
  __shared__ uint4 lm4[1024];      // 16 KB  M tile
  int t = threadIdx.x;
  int pb = blockIdx.x >> 1;        // pixel-block 0..511
  int half = blockIdx.x & 1;       // output half
  int n0 = pb << 7;

#pragma unroll
  for (int i = 0; i < 4; i++) {
    int idx = t + i * 256;
    int row = idx >> 3;
    int kq = idx & 7;
    lx4[(row << 3) | (kq ^ (row & 7))] = X1p4[(n0 << 3) + idx];
  }

  int oc_t = t & 15;               // output-thread 0..15 (owns 8 outs, stride 16)
  int pr_t = t >> 4;               // pixel-thread 0..15 (owns 8 px, stride 16)
  int pgrp = pr_t & 3;             // pixel group within wave
  int sx = pr_t & 7;               // X-tile swizzle key (const per thread)
  int so = oc_t & 7;               // M-tile swizzle key

  for (int oc4 = 0; oc4 < 4; oc4++) {
    int oc = half * 4 + oc4;       // global 128-out chunk index 0..7
    __syncthreads();               // protect lm4 from previous iteration
#pragma unroll
    for (int i = 0; i < 4; i++) {
      int idx = t + i * 256;
      int row = idx >> 3;
      int kq = idx & 7;
      lm4[(row << 3) | (kq ^ (row & 7))] = M1p4[(oc << 10) + idx];
    }
    __syncthreads();

    unsigned acc[8][8];
#pragma unroll
    for (int i = 0; i < 8; i++)
#pragma unroll
      for (int j = 0; j < 8; j++) acc[i][j] = 0;

#pragma unroll 1
    for (int kq = 0; kq < 8; kq++) {
      const uint4* xp = &lx4[(pr_t << 3) + (kq ^ sx)];
      const uint4* mp = &lm4[(oc_t << 3) + (kq ^ so)];
      uint4 xv[8];
#pragma unroll
      for (int i = 0; i < 8; i++) xv[i] = xp[i << 7];   // +2048B immediates
#pragma unroll
      for (int j = 0; j < 8; j++) {
        uint4 mv = mp[j << 7];                          // streamed, ~4 regs live
#pragma unroll
        for (int i = 0; i < 8; i++) {
          acc[i][j] += __popc(xv[i].x ^ mv.x);
          acc[i][j] += __popc(xv[i].y ^ mv.y);
          acc[i][j] += __popc(xv[i].z ^ mv.z);
          acc[i][j] += __popc(xv[i].w ^ mv.w);
        }
      }
    }

    // threshold + ballot-pack x2 bits -> global X2p[n][kw] (kw = oc*4+wd)
    int limv[8];
#pragma unroll
    for (int j = 0; j < 8; j++)
      limv[j] = 1024 - thr1[(oc << 7) + (j << 4) + oc_t];
#pragma unroll
    for (int i = 0; i < 8; i++) {
      unsigned wacc[4] = {0, 0, 0, 0};
#pragma unroll
      for (int j = 0; j < 8; j++) {
        bool bit = ((int)acc[i][j]) < limv[j];          // 1024-acc > thr1
        unsigned long long bal = __ballot(bit);
        unsigned hw16 = (unsigned)(bal >> (pgrp << 4)) & 0xFFFFu;
        wacc[j >> 1] |= hw16 << ((j & 1) << 4);
      }
      if (oc_t == 0) {
        int n = n0 + pr_t + (i << 4);
        uint4 v; v.x = wacc[0]; v.y = wacc[1]; v.z = wacc[2]; v.w = wacc[3];
        *reinterpret_cast<uint4*>(&X2p[(unsigned)n * 32 + (oc << 2)]) = v;
      }
    }
  }
}

// Layer 2 + epilogue: 256 px/block, one px/thread. x2 row read as 8x uint4
// (coalesced); lm2 accesses are wave-uniform -> LDS broadcast (free).
__global__ __launch_bounds__(256) void l2_kernel(
    const uint4* __restrict__ X2p4, const unsigned* __restrict__ M2p,
    const int* __restrict__ thr2, const float* __restrict__ image,
    float* __restrict__ out) {
  __shared__ unsigned lm2[768];
  int t = threadIdx.x;
  for (int r = t; r < 768; r += 256) lm2[r] = M2p[r];
  __syncthreads();
  int n = blockIdx.x * 256 + t;
  uint4 xw[8];
#pragma unroll
  for (int q = 0; q < 8; q++) xw[q] = X2p4[(unsigned)n * 8 + q];
#pragma unroll
  for (int c = 0; c < 3; c++) {
    int val = 0;
#pragma unroll
    for (int b = 0; b < 8; b++) {
      int o = c * 8 + b;
      const unsigned* m = &lm2[o * 32];
      unsigned acc2 = 0;
#pragma unroll
      for (int q = 0; q < 8; q++) {
        acc2 += __popc(xw[q].x ^ m[q * 4 + 0]);
        acc2 += __popc(xw[q].y ^ m[q * 4 + 1]);
        acc2 += __popc(xw[q].z ^ m[q * 4 + 2]);
        acc2 += __popc(xw[q].w ^ m[q * 4 + 3]);
      }
      int bit = ((int)(1024u - acc2)) > thr2[o];
      val |= bit << (7 - b);                            // MSB-first
    }
    out[c * 65536 + n] = (float)val;
    out[196608 + c * 65536 + n] = (float)val - image[c * 65536 + n];
  }
}

extern "C" void kernel_launch(void* const* d_in, const int* in_sizes, int n_in,
                              void* d_out, int out_size, void* d_ws, size_t ws_size,
                              hipStream_t stream) {
  const float*         image = (const float*)d_in[0];
  const unsigned char* mask0 = (const unsigned char*)d_in[1];
  const int*           thr0  = (const int*)d_in[2];
  const unsigned char* mask1 = (const unsigned char*)d_in[3];
  const int*           thr1  = (const int*)d_in[4];
  const unsigned char* mask2 = (const unsigned char*)d_in[5];
  const int*           thr2  = (const int*)d_in[6];
  char* ws = (char*)d_ws;
  unsigned*      X1p = (unsigned*)(ws);
  signed char*   cA  = (signed char*)(ws + WS_CA);
  unsigned char* cB  = (unsigned char*)(ws + WS_CB);
  unsigned*      M1p = (unsigned*)(ws + WS_M1);
  unsigned*      M2p = (unsigned*)(ws + WS_M2);
  unsigned*      X2p = (unsigned*)(ws + WS_X2);
  float* out = (float*)d_out;

  hipLaunchKernelGGL(prep_kernel, dim3(2179), dim3(256), 0, stream,
                     mask0, thr0, mask1, mask2, cA, cB, M1p, M2p);
  hipLaunchKernelGGL(pack_x1, dim3(4096), dim3(256), 0, stream, cA, cB, X1p);
  hipLaunchKernelGGL(main_kernel, dim3(1024), dim3(256), 0, stream,
                     (const uint4*)X1p, (const uint4*)M1p, thr1, X2p);
  hipLaunchKernelGGL(l2_kernel, dim3(256), dim3(256), 0, stream,
                     (const uint4*)X2p, M2p, thr2, image, out);
}

// Round 8
// 212.615 us; speedup vs baseline: 7.2337x; 1.0248x over previous
//
#include <hip/hip_runtime.h>
#include <stdint.h>

// 3-layer binary net as XNOR-popcount on bit-packed vectors.
// ws: X1p 65536*32 u32 @0 (8MB) | cA 256*1024 s8 | cB 256*1024 u8 |
//     M1p 1024*32 u32 | M2p 24*32 u32 | X2p 65536*32 u32 (8MB)
#define WS_CA  8388608
#define WS_CB  8650752
#define WS_M1  8912896
#define WS_M2  9043968
#define WS_X2  9047040

// ---- mask upload-format sniffing (bool arrays may arrive as u8, i32, or f32) ----
// R8: runs ONCE PER BLOCK (was per-thread: 557k threads x ~80 loads = the
// hidden ~70us of prep time in R2-R7).
__device__ inline int detect_mode(const unsigned char* p) {
  unsigned nonalign = 0;
  for (int i = 0; i < 64; i++)
    if (i & 3) nonalign |= p[i];
  if (nonalign == 0) return 1;                 // int32 0/1
  bool f32ok = true;
  for (int e = 0; e < 16; e++) {
    const unsigned char* q = p + 4 * e;
    bool one  = (q[0] == 0 && q[1] == 0 && q[2] == 0x80 && q[3] == 0x3F);
    bool zero = (q[0] == 0 && q[1] == 0 && q[2] == 0 && q[3] == 0);
    if (!(one || zero)) { f32ok = false; break; }
  }
  return f32ok ? 2 : 0;
}

__device__ inline int maskbit(const unsigned char* p, int idx, int mode) {
  if (mode == 1) return ((const int*)p)[idx] & 1;
  if (mode == 2) return ((const float*)p)[idx] != 0.0f;
  return p[idx] & 1;
}

__global__ __launch_bounds__(256) void prep_kernel(
    const unsigned char* __restrict__ mask0, const int* __restrict__ thr0,
    const unsigned char* __restrict__ mask1, const unsigned char* __restrict__ mask2,
    signed char* __restrict__ cA, unsigned char* __restrict__ cB,
    unsigned* __restrict__ M1p, unsigned* __restrict__ M2p) {
  __shared__ int smode;
  if (threadIdx.x == 0) smode = detect_mode(mask1);   // one sniff per block
  __syncthreads();
  int mode = smode;
  int gid = blockIdx.x * 256 + threadIdx.x;
  if (gid < 524288) {              // cA / cB tables (mask0 16KB, L2-hot)
    int which = gid >> 18;         // 0 = cA (h-bits), 1 = cB (w-bits)
    int idx = gid & 262143;
    int hw = idx >> 10;
    int o  = idx & 1023;
    int base = which ? 8 : 0;
    int cnt = 0;
#pragma unroll
    for (int i = 0; i < 8; i++) {
      int xb = (hw >> (7 - i)) & 1;                     // MSB-first bits
      int mb = maskbit(mask0, (base + i) * 1024 + o, mode);
      cnt += (xb == mb);
    }
    if (which) cB[idx] = (unsigned char)cnt;
    else       cA[idx] = (signed char)(cnt - thr0[o]);  // fold threshold in
    return;
  }
  int g2 = gid - 524288;
  if (g2 < 32768) {                // pack mask1: M1p[o][kw]; lanes->consecutive o = coalesced
    int kw = g2 >> 10, o = g2 & 1023;
    unsigned wv = 0;
#pragma unroll
    for (int b = 0; b < 32; b++)
      wv |= (unsigned)maskbit(mask1, (kw * 32 + b) * 1024 + o, mode) << b;  // LSB-first
    M1p[o * 32 + kw] = wv;
    return;
  }
  int g3 = g2 - 32768;
  if (g3 < 768) {                  // pack mask2: M2p[o][kw]
    int kw = g3 / 24, o = g3 % 24;
    unsigned wv = 0;
    for (int b = 0; b < 32; b++)
      wv |= (unsigned)maskbit(mask2, (kw * 32 + b) * 24 + o, mode) << b;
    M2p[o * 32 + kw] = wv;
  }
}

// Layer-0 evaluate + bit-pack. Block = (h, w/16): 16 pixels -> 4096 blocks.
__global__ __launch_bounds__(256) void pack_x1(
    const signed char* __restrict__ cA, const unsigned char* __restrict__ cB,
    unsigned* __restrict__ X1p) {
  int t = threadIdx.x;
  int lane = t & 63;
  int q = t >> 6;                  // wave id in block
  int h = blockIdx.x >> 4;
  int w0 = (blockIdx.x & 15) << 4;
  const signed char* ca = cA + h * 1024;
  for (int wi = 0; wi < 16; wi++) {
    int w = w0 + wi;
    const unsigned char* cb = cB + w * 1024;
    int n = h * 256 + w;
#pragma unroll
    for (int j = 0; j < 4; j++) {
      int o = j * 256 + t;
      bool bit = ((int)ca[o] + (int)cb[o]) > 0;        // cA+cB > thr0
      unsigned long long bal = __ballot(bit);
      if (lane == 0) {
        uint2 v; v.x = (unsigned)bal; v.y = (unsigned)(bal >> 32);
        *reinterpret_cast<uint2*>(&X1p[n * 32 + j * 8 + q * 2]) = v;
      }
    }
  }
}

// Main: L1 popcount-GEMM. Block = 128px x 512out, grid 1024 (4 blocks/CU),
// per oc-iteration 128x128, per-thread 8x8 acc. Lessons R3-R6: no VGPR cap
// below live set; kq as a real loop (#pragma unroll 1). VGPR must stay <=128
// (4 waves/SIMD cliff). uint4-granular XOR swizzle kq^=(row&7).
__global__ __launch_bounds__(256) void main_kernel(
    const uint4* __restrict__ X1p4, const uint4* __restrict__ M1p4,
    const int* __restrict__ thr1, unsigned* __restrict__ X2p) {
  __shared__ uint4 lx4[1024];      // 16 KB  X tile  [row][kq^(row&7)]
  __shared__ uint4 lm4[1024];      // 16 KB  M tile
  int t = threadIdx.x;
  int pb = blockIdx.x >> 1;        // pixel-block 0..511
  int half = blockIdx.x & 1;       // output half
  int n0 = pb << 7;

#pragma unroll
  for (int i = 0; i < 4; i++) {
    int idx = t + i * 256;
    int row = idx >> 3;
    int kq = idx & 7;
    lx4[(row << 3) | (kq ^ (row & 7))] = X1p4[(n0 << 3) + idx];
  }

  int oc_t = t & 15;               // output-thread 0..15 (owns 8 outs, stride 16)
  int pr_t = t >> 4;               // pixel-thread 0..15 (owns 8 px, stride 16)
  int pgrp = pr_t & 3;             // pixel group within wave
  int sx = pr_t & 7;               // X-tile swizzle key (const per thread)
  int so = oc_t & 7;               // M-tile swizzle key

  for (int oc4 = 0; oc4 < 4; oc4++) {
    int oc = half * 4 + oc4;       // global 128-out chunk index 0..7
    __syncthreads();               // protect lm4 from previous iteration
#pragma unroll
    for (int i = 0; i < 4; i++) {
      int idx = t + i * 256;
      int row = idx >> 3;
      int kq = idx & 7;
      lm4[(row << 3) | (kq ^ (row & 7))] = M1p4[(oc << 10) + idx];
    }
    __syncthreads();

    unsigned acc[8][8];
#pragma unroll
    for (int i = 0; i < 8; i++)
#pragma unroll
      for (int j = 0; j < 8; j++) acc[i][j] = 0;

#pragma unroll 1
    for (int kq = 0; kq < 8; kq++) {
      const uint4* xp = &lx4[(pr_t << 3) + (kq ^ sx)];
      const uint4* mp = &lm4[(oc_t << 3) + (kq ^ so)];
      uint4 xv[8];
#pragma unroll
      for (int i = 0; i < 8; i++) xv[i] = xp[i << 7];   // +2048B immediates
      uint4 mvn = mp[0];
#pragma unroll
      for (int j = 0; j < 8; j++) {
        uint4 mv = mvn;
        if (j < 7) mvn = mp[(j + 1) << 7];              // 1-deep prefetch
#pragma unroll
        for (int i = 0; i < 8; i++) {
          acc[i][j] += __popc(xv[i].x ^ mv.x);
          acc[i][j] += __popc(xv[i].y ^ mv.y);
          acc[i][j] += __popc(xv[i].z ^ mv.z);
          acc[i][j] += __popc(xv[i].w ^ mv.w);
        }
      }
    }

    // threshold + ballot-pack x2 bits -> global X2p[n][kw] (kw = oc*4+wd)
    int limv[8];
#pragma unroll
    for (int j = 0; j < 8; j++)
      limv[j] = 1024 - thr1[(oc << 7) + (j << 4) + oc_t];
#pragma unroll
    for (int i = 0; i < 8; i++) {
      unsigned wacc[4] = {0, 0, 0, 0};
#pragma unroll
      for (int j = 0; j < 8; j++) {
        bool bit = ((int)acc[i][j]) < limv[j];          // 1024-acc > thr1
        unsigned long long bal = __ballot(bit);
        unsigned hw16 = (unsigned)(bal >> (pgrp << 4)) & 0xFFFFu;
        wacc[j >> 1] |= hw16 << ((j & 1) << 4);
      }
      if (oc_t == 0) {
        int n = n0 + pr_t + (i << 4);
        uint4 v; v.x = wacc[0]; v.y = wacc[1]; v.z = wacc[2]; v.w = wacc[3];
        *reinterpret_cast<uint4*>(&X2p[(unsigned)n * 32 + (oc << 2)]) = v;
      }
    }
  }
}

// Layer 2 + epilogue: 256 px/block, one px/thread.
__global__ __launch_bounds__(256) void l2_kernel(
    const uint4* __restrict__ X2p4, const unsigned* __restrict__ M2p,
    const int* __restrict__ thr2, const float* __restrict__ image,
    float* __restrict__ out) {
  __shared__ unsigned lm2[768];
  int t = threadIdx.x;
  for (int r = t; r < 768; r += 256) lm2[r] = M2p[r];
  __syncthreads();
  int n = blockIdx.x * 256 + t;
  uint4 xw[8];
#pragma unroll
  for (int q = 0; q < 8; q++) xw[q] = X2p4[(unsigned)n * 8 + q];
#pragma unroll
  for (int c = 0; c < 3; c++) {
    int val = 0;
#pragma unroll
    for (int b = 0; b < 8; b++) {
      int o = c * 8 + b;
      const unsigned* m = &lm2[o * 32];
      unsigned acc2 = 0;
#pragma unroll
      for (int q = 0; q < 8; q++) {
        acc2 += __popc(xw[q].x ^ m[q * 4 + 0]);
        acc2 += __popc(xw[q].y ^ m[q * 4 + 1]);
        acc2 += __popc(xw[q].z ^ m[q * 4 + 2]);
        acc2 += __popc(xw[q].w ^ m[q * 4 + 3]);
      }
      int bit = ((int)(1024u - acc2)) > thr2[o];
      val |= bit << (7 - b);                            // MSB-first
    }
    out[c * 65536 + n] = (float)val;
    out[196608 + c * 65536 + n] = (float)val - image[c * 65536 + n];
  }
}

extern "C" void kernel_launch(void* const* d_in, const int* in_sizes, int n_in,
                              void* d_out, int out_size, void* d_ws, size_t ws_size,
                              hipStream_t stream) {
  const float*         image = (const float*)d_in[0];
  const unsigned char* mask0 = (const unsigned char*)d_in[1];
  const int*           thr0  = (const int*)d_in[2];
  const unsigned char* mask1 = (const unsigned char*)d_in[3];
  const int*           thr1  = (const int*)d_in[4];
  const unsigned char* mask2 = (const unsigned char*)d_in[5];
  const int*           thr2  = (const int*)d_in[6];
  char* ws = (char*)d_ws;
  unsigned*      X1p = (unsigned*)(ws);
  signed char*   cA  = (signed char*)(ws + WS_CA);
  unsigned char* cB  = (unsigned char*)(ws + WS_CB);
  unsigned*      M1p = (unsigned*)(ws + WS_M1);
  unsigned*      M2p = (unsigned*)(ws + WS_M2);
  unsigned*      X2p = (unsigned*)(ws + WS_X2);
  float* out = (float*)d_out;

  hipLaunchKernelGGL(prep_kernel, dim3(2179), dim3(256), 0, stream,
                     mask0, thr0, mask1, mask2, cA, cB, M1p, M2p);
  hipLaunchKernelGGL(pack_x1, dim3(4096), dim3(256), 0, stream, cA, cB, X1p);
  hipLaunchKernelGGL(main_kernel, dim3(1024), dim3(256), 0, stream,
                     (const uint4*)X1p, (const uint4*)M1p, thr1, X2p);
  hipLaunchKernelGGL(l2_kernel, dim3(256), dim3(256), 0, stream,
                     (const uint4*)X2p, M2p, thr2, image, out);
}